// Round 4
// baseline (442.425 us; speedup 1.0000x reference)
//
#include <hip/hip_runtime.h>

#define NH 1024   // hidden
#define NI2 2048  // 2*intermediate
#define NI 1024   // intermediate
#define NE 16     // experts
#define NT 1024   // tokens (2*512)

static constexpr float LIMITF = 7.0f;
static constexpr float ALPHAF = 1.702f;
static constexpr float EPSF = 1e-5f;

typedef short bf16x8 __attribute__((ext_vector_type(8)));
typedef float f32x16 __attribute__((ext_vector_type(16)));

__device__ __forceinline__ unsigned short f2bf(float f) {
  unsigned int u = __builtin_bit_cast(unsigned int, f);
  u = (u + 0x7FFFu + ((u >> 16) & 1u)) >> 16;
  return (unsigned short)u;
}

// async 16B global -> LDS (DMA path, no VGPR round-trip). Deep vmcnt queue
// gives ~16KB in flight per block vs ~2-4KB with VGPR-buffered loads.
typedef __attribute__((address_space(1))) const unsigned int as1_uint;
typedef __attribute__((address_space(3))) unsigned int as3_uint;
__device__ __forceinline__ void gload16(const void* g, void* l) {
  __builtin_amdgcn_global_load_lds((as1_uint*)g, (as3_uint*)l, 16, 0, 0);
}

// ---------------- out = x (residual base) ----------------
__global__ __launch_bounds__(256) void k_init(const float* __restrict__ x,
                                              float* __restrict__ out) {
  int i = blockIdx.x * 256 + threadIdx.x;
  reinterpret_cast<float4*>(out)[i] = reinterpret_cast<const float4*>(x)[i];
}

// ---------------- RMSNorm + router ----------------
__global__ __launch_bounds__(256) void k_norm_router(
    const float* __restrict__ x, const float* __restrict__ nsc,
    const float* __restrict__ wg, const float* __restrict__ bg,
    unsigned short* __restrict__ xn, int* __restrict__ topk_idx,
    float* __restrict__ topk_gate, int* __restrict__ counts) {
  int t = blockIdx.x;
  int tid = threadIdx.x;
  int wave = tid >> 6, lane = tid & 63;

  float4 v = reinterpret_cast<const float4*>(x + (size_t)t * NH)[tid];
  float ss = v.x * v.x + v.y * v.y + v.z * v.z + v.w * v.w;
  for (int off = 32; off; off >>= 1) ss += __shfl_xor(ss, off);

  __shared__ float red[4];
  __shared__ float redl[4][16];
  __shared__ float logits_s[16];
  if (lane == 0) red[wave] = ss;
  __syncthreads();
  float tot = red[0] + red[1] + red[2] + red[3];
  float r = rsqrtf(tot * (1.0f / NH) + EPSF);

  float4 sc = reinterpret_cast<const float4*>(nsc)[tid];
  float xv[4];
  xv[0] = v.x * r * sc.x;
  xv[1] = v.y * r * sc.y;
  xv[2] = v.z * r * sc.z;
  xv[3] = v.w * r * sc.w;

  ushort4 o;
  o.x = f2bf(xv[0]); o.y = f2bf(xv[1]); o.z = f2bf(xv[2]); o.w = f2bf(xv[3]);
  reinterpret_cast<ushort4*>(xn + (size_t)t * NH)[tid] = o;

  float acc[16];
#pragma unroll
  for (int e = 0; e < 16; e++) acc[e] = 0.f;
  int hbase = tid * 4;
#pragma unroll
  for (int i = 0; i < 4; i++) {
    const float4* wr = reinterpret_cast<const float4*>(wg + (size_t)(hbase + i) * NE);
#pragma unroll
    for (int j = 0; j < 4; j++) {
      float4 w = wr[j];
      acc[j * 4 + 0] += xv[i] * w.x;
      acc[j * 4 + 1] += xv[i] * w.y;
      acc[j * 4 + 2] += xv[i] * w.z;
      acc[j * 4 + 3] += xv[i] * w.w;
    }
  }
#pragma unroll
  for (int e = 0; e < 16; e++)
    for (int off = 32; off; off >>= 1) acc[e] += __shfl_xor(acc[e], off);
  if (lane == 0) {
#pragma unroll
    for (int e = 0; e < 16; e++) redl[wave][e] = acc[e];
  }
  __syncthreads();
  if (tid < 16)
    logits_s[tid] = redl[0][tid] + redl[1][tid] + redl[2][tid] + redl[3][tid] + bg[tid];
  __syncthreads();

  if (tid == 0) {
    float vals[16];
#pragma unroll
    for (int e = 0; e < 16; e++) vals[e] = logits_s[e];
    int sel[4]; float sv[4];
    unsigned used = 0;
    for (int k = 0; k < 4; k++) {
      float best = -1e30f; int bi = 0;
      for (int e = 0; e < 16; e++) {
        if (!((used >> e) & 1u) && vals[e] > best) { best = vals[e]; bi = e; }
      }
      used |= 1u << bi; sel[k] = bi; sv[k] = best;
    }
    float g[4], ssum = 0.f;
    for (int k = 0; k < 4; k++) { g[k] = __expf(sv[k] - sv[0]); ssum += g[k]; }
    for (int k = 0; k < 4; k++) {
      topk_idx[t * 4 + k] = sel[k];
      topk_gate[t * 4 + k] = g[k] / ssum;
      atomicAdd(&counts[sel[k]], 1);
    }
  }
}

// ---------------- prefix scan over 16 experts (32-aligned offsets) -------
// Total padded slots <= 4096 + 16*31 = 4576; rows_tok/rows_gate reserve 5120.
__global__ void k_scan(const int* __restrict__ counts, int* __restrict__ offsets,
                       int* __restrict__ cursor) {
  if (blockIdx.x == 0 && threadIdx.x == 0) {
    int o = 0;
    for (int e = 0; e < NE; e++) {
      offsets[e] = o; cursor[e] = o;
      o += (counts[e] + 31) & ~31;   // pad each expert range to 32 slots
    }
  }
}

// ---------------- fill compact per-expert row lists ----------------
__global__ __launch_bounds__(256) void k_fill(const int* __restrict__ topk_idx,
                                              const float* __restrict__ topk_gate,
                                              int* __restrict__ cursor,
                                              int* __restrict__ rows_tok,
                                              float* __restrict__ rows_gate) {
  int idx = blockIdx.x * 256 + threadIdx.x;
  if (idx >= NT * 4) return;
  int e = topk_idx[idx];
  int slot = atomicAdd(&cursor[e], 1);
  rows_tok[slot] = idx >> 2;
  rows_gate[slot] = topk_gate[idx];
}

// ---------------- gather routed activations into MFMA-tiled layout ------
// xg layout: [group][k-octet 0..127][row-in-group 0..31][8 bf16]
__global__ __launch_bounds__(256) void k_gather(
    const unsigned short* __restrict__ xn, const int* __restrict__ counts,
    const int* __restrict__ offsets, const int* __restrict__ rows_tok,
    unsigned short* __restrict__ xg) {
  int e = blockIdx.y;
  int g = blockIdx.x;
  int cnt = counts[e];
  if (g * 32 >= cnt) return;
  int tid = threadIdx.x;
  int r = tid & 31, kq = tid >> 5;
  int rowbase = offsets[e];
  int tok = rows_tok[rowbase + min(g * 32 + r, cnt - 1)];
  const uint4* src = reinterpret_cast<const uint4*>(xn + (size_t)tok * NH);
  uint4* dst = reinterpret_cast<uint4*>(
      xg + ((size_t)(rowbase >> 5) + g) * (128 * 32 * 8));
#pragma unroll
  for (int i = 0; i < 16; i++) {
    int ko = i * 8 + kq;        // k-octet 0..127
    dst[ko * 32 + r] = src[ko]; // raw bf16x8 copy
  }
}

// Async-staged panel build: 8 rounds of {issue 16KB global_load_lds ->
// sync (drains vmcnt) -> LDS fp32 -> bf16 panel convert -> sync}.
// fbuf holds 128 rows x 32 cols fp32 (row-major, 16B granule = 4 cols,
// contiguous in global). panel keeps the proven [k8][col][8] bf16 layout.
template <int ROWSTRIDE>  // floats per source row (NI2 for w1, NH for w2)
__device__ __forceinline__ void stage_panel_async(
    const float* __restrict__ wsrc, unsigned short* __restrict__ panel,
    float* __restrict__ fbuf, int tid) {
  int colq = tid & 7;    // 16B quad within 128B row
  int rquot = tid >> 3;  // 0..31
  int col = tid & 31;
  int oct = tid >> 5;    // 0..7
  for (int r = 0; r < 8; r++) {
#pragma unroll
    for (int i = 0; i < 4; i++) {
      int row = r * 128 + i * 32 + rquot;
      gload16(wsrc + (size_t)row * ROWSTRIDE + colq * 4,
              (char*)fbuf + tid * 16 + i * 4096);
    }
    __syncthreads();  // compiler drains vmcnt(0) before s_barrier (m97)
#pragma unroll
    for (int oo = 0; oo < 2; oo++) {
      int o = oct + oo * 8;
      float f[8];
#pragma unroll
      for (int j = 0; j < 8; j++) f[j] = fbuf[(o * 8 + j) * 32 + col];
      unsigned pk[4];
#pragma unroll
      for (int j = 0; j < 4; j++)
        pk[j] = (unsigned)f2bf(f[2 * j]) | ((unsigned)f2bf(f[2 * j + 1]) << 16);
      *reinterpret_cast<uint4*>(&panel[(size_t)((r * 16 + o) * 32 + col) * 8]) =
          *reinterpret_cast<const uint4*>(pk);
    }
    __syncthreads();  // fbuf reuse protection
  }
}

// ---------------- FFN1: one block per (expert, 32-col strip of w1) ------
__global__ __launch_bounds__(256) void k_ffn1(
    const unsigned short* __restrict__ xg, const float* __restrict__ w1,
    const float* __restrict__ b1, const int* __restrict__ counts,
    const int* __restrict__ offsets, unsigned short* __restrict__ s_tiled) {
  int e = blockIdx.y;
  int cnt = counts[e];
  if (cnt == 0) return;
  int n0 = blockIdx.x * 32;
  int rowbase = offsets[e];
  int tid = threadIdx.x;

  // 64 KB bf16 panel + 16 KB fp32 bounce = 80 KB -> 2 blocks/CU
  __shared__ __align__(16) unsigned short lds_b[128 * 32 * 8];
  __shared__ __align__(16) float lds_f[128 * 32];

  stage_panel_async<NI2>(w1 + (size_t)e * (NH * NI2) + n0, lds_b, lds_f, tid);

  int lane = tid & 63;
  int wave = tid >> 6;
  int lrow = lane & 31;
  int khalf = lane >> 5;

  float bias = b1[(size_t)e * NI2 + n0 + lrow];
  int parity = lrow & 1;

  for (int m0 = 0; m0 < cnt; m0 += 256) {
    int tb0 = m0 + wave * 32;
    int tb1 = m0 + 128 + wave * 32;
    const unsigned short* a0p =
        xg + ((size_t)((rowbase + tb0) >> 5) * 128 + khalf) * 256 + lrow * 8;

    f32x16 acc0 = {0.f,0.f,0.f,0.f,0.f,0.f,0.f,0.f,0.f,0.f,0.f,0.f,0.f,0.f,0.f,0.f};
    f32x16 acc1 = {0.f,0.f,0.f,0.f,0.f,0.f,0.f,0.f,0.f,0.f,0.f,0.f,0.f,0.f,0.f,0.f};
    bool dual = (m0 + 128) < cnt;

    if (dual) {
      const unsigned short* a1p =
          xg + ((size_t)((rowbase + tb1) >> 5) * 128 + khalf) * 256 + lrow * 8;
#pragma unroll 4
      for (int k2 = 0; k2 < 64; k2++) {
        bf16x8 av0 = *reinterpret_cast<const bf16x8*>(a0p + k2 * 512);
        bf16x8 av1 = *reinterpret_cast<const bf16x8*>(a1p + k2 * 512);
        bf16x8 bv = *reinterpret_cast<const bf16x8*>(
            &lds_b[(size_t)((k2 * 2 + khalf) * 32 + lrow) * 8]);
        acc0 = __builtin_amdgcn_mfma_f32_32x32x16_bf16(av0, bv, acc0, 0, 0, 0);
        acc1 = __builtin_amdgcn_mfma_f32_32x32x16_bf16(av1, bv, acc1, 0, 0, 0);
      }
    } else {
#pragma unroll 4
      for (int k2 = 0; k2 < 64; k2++) {
        bf16x8 av0 = *reinterpret_cast<const bf16x8*>(a0p + k2 * 512);
        bf16x8 bv = *reinterpret_cast<const bf16x8*>(
            &lds_b[(size_t)((k2 * 2 + khalf) * 32 + lrow) * 8]);
        acc0 = __builtin_amdgcn_mfma_f32_32x32x16_bf16(av0, bv, acc0, 0, 0, 0);
      }
    }

#pragma unroll
    for (int t2 = 0; t2 < 2; t2++) {
      if (t2 == 1 && !dual) break;
      f32x16 acc = t2 ? acc1 : acc0;
      int tb = t2 ? tb1 : tb0;
#pragma unroll
      for (int reg = 0; reg < 16; reg++) {
        float v = acc[reg] + bias;
        float p = __shfl_xor(v, 1);
        int row = (reg & 3) + 8 * (reg >> 2) + 4 * khalf;
        int m = tb + row;
        if (!parity && m < cnt) {
          float aa = fminf(v, LIMITF);
          float bb = fminf(fmaxf(p, -LIMITF), LIMITF);
          float sig = 1.0f / (1.0f + __expf(-ALPHAF * aa));
          float sval = aa * sig * (bb + 1.0f);
          int c = (n0 + lrow) >> 1;  // intermediate column
          size_t grp = (size_t)(rowbase + tb) >> 5;
          s_tiled[(grp * 128 + (c >> 3)) * 256 + row * 8 + (c & 7)] = f2bf(sval);
        }
      }
    }
  }
}

// ---------------- FFN2: one block per (expert, 32-col strip of w2) ------
__global__ __launch_bounds__(256) void k_ffn2(
    const unsigned short* __restrict__ s_tiled, const float* __restrict__ w2,
    const float* __restrict__ b2, const int* __restrict__ counts,
    const int* __restrict__ offsets, const int* __restrict__ rows_tok,
    const float* __restrict__ rows_gate, float* __restrict__ out) {
  int e = blockIdx.y;
  int cnt = counts[e];
  if (cnt == 0) return;
  int n0 = blockIdx.x * 32;
  int rowbase = offsets[e];
  int tid = threadIdx.x;

  __shared__ __align__(16) unsigned short lds_b[128 * 32 * 8];
  __shared__ __align__(16) float lds_f[128 * 32];

  stage_panel_async<NH>(w2 + (size_t)e * (NI * NH) + n0, lds_b, lds_f, tid);

  int lane = tid & 63;
  int wave = tid >> 6;
  int lrow = lane & 31;
  int khalf = lane >> 5;

  float b2v = b2[(size_t)e * NH + n0 + lrow];

  for (int m0 = 0; m0 < cnt; m0 += 256) {
    int tb0 = m0 + wave * 32;
    int tb1 = m0 + 128 + wave * 32;
    const unsigned short* a0p =
        s_tiled + ((size_t)((rowbase + tb0) >> 5) * 128 + khalf) * 256 + lrow * 8;

    f32x16 acc0 = {0.f,0.f,0.f,0.f,0.f,0.f,0.f,0.f,0.f,0.f,0.f,0.f,0.f,0.f,0.f,0.f};
    f32x16 acc1 = {0.f,0.f,0.f,0.f,0.f,0.f,0.f,0.f,0.f,0.f,0.f,0.f,0.f,0.f,0.f,0.f};
    bool dual = (m0 + 128) < cnt;

    if (dual) {
      const unsigned short* a1p =
          s_tiled + ((size_t)((rowbase + tb1) >> 5) * 128 + khalf) * 256 + lrow * 8;
#pragma unroll 4
      for (int k2 = 0; k2 < 64; k2++) {
        bf16x8 av0 = *reinterpret_cast<const bf16x8*>(a0p + k2 * 512);
        bf16x8 av1 = *reinterpret_cast<const bf16x8*>(a1p + k2 * 512);
        bf16x8 bv = *reinterpret_cast<const bf16x8*>(
            &lds_b[(size_t)((k2 * 2 + khalf) * 32 + lrow) * 8]);
        acc0 = __builtin_amdgcn_mfma_f32_32x32x16_bf16(av0, bv, acc0, 0, 0, 0);
        acc1 = __builtin_amdgcn_mfma_f32_32x32x16_bf16(av1, bv, acc1, 0, 0, 0);
      }
    } else {
#pragma unroll 4
      for (int k2 = 0; k2 < 64; k2++) {
        bf16x8 av0 = *reinterpret_cast<const bf16x8*>(a0p + k2 * 512);
        bf16x8 bv = *reinterpret_cast<const bf16x8*>(
            &lds_b[(size_t)((k2 * 2 + khalf) * 32 + lrow) * 8]);
        acc0 = __builtin_amdgcn_mfma_f32_32x32x16_bf16(av0, bv, acc0, 0, 0, 0);
      }
    }

#pragma unroll
    for (int t2 = 0; t2 < 2; t2++) {
      if (t2 == 1 && !dual) break;
      f32x16 acc = t2 ? acc1 : acc0;
      int tb = t2 ? tb1 : tb0;
#pragma unroll
      for (int reg = 0; reg < 16; reg++) {
        int row = (reg & 3) + 8 * (reg >> 2) + 4 * khalf;
        int m = tb + row;
        if (m < cnt) {
          int rr = rowbase + m;           // wave-uniform per (reg,khalf)
          int tok = rows_tok[rr];
          float g = rows_gate[rr];
          atomicAdd(&out[(size_t)tok * NH + n0 + lrow], g * (acc[reg] + b2v));
        }
      }
    }
  }
}

extern "C" void kernel_launch(void* const* d_in, const int* in_sizes, int n_in,
                              void* d_out, int out_size, void* d_ws, size_t ws_size,
                              hipStream_t stream) {
  const float* x   = (const float*)d_in[0];
  const float* nsc = (const float*)d_in[1];
  const float* wg  = (const float*)d_in[2];
  const float* bg  = (const float*)d_in[3];
  const float* w1  = (const float*)d_in[4];
  const float* b1  = (const float*)d_in[5];
  const float* w2  = (const float*)d_in[6];
  const float* b2  = (const float*)d_in[7];
  float* out = (float*)d_out;
  char* ws = (char*)d_ws;

  // Workspace map (worst case 4576 padded slots = 143 groups):
  //   0       counts/offsets/cursor (zeroed)
  //   1024    topk_idx   16 KB
  //   17408   topk_gate  16 KB
  //   33792   rows_tok   20 KB (5120 slots >= 4576)
  //   54272   rows_gate  20 KB (5120 slots)
  //   131072  xn         2 MB
  //   2228224 xg         143*64KB = 9.15 MB
  //   12 MB   s_tiled    9.15 MB
  int*   counts    = (int*)(ws + 0);
  int*   offsets   = (int*)(ws + 64);
  int*   cursor    = (int*)(ws + 128);
  int*   topk_idx  = (int*)(ws + 1024);
  float* topk_gate = (float*)(ws + 17408);
  int*   rows_tok  = (int*)(ws + 33792);
  float* rows_gate = (float*)(ws + 54272);
  unsigned short* xn      = (unsigned short*)(ws + 131072);
  unsigned short* xg      = (unsigned short*)(ws + 2228224);
  unsigned short* s_tiled = (unsigned short*)(ws + 12 * 1024 * 1024);

  hipMemsetAsync(ws, 0, 256, stream);
  k_init<<<NT * NH / 1024, 256, 0, stream>>>(x, out);
  k_norm_router<<<NT, 256, 0, stream>>>(x, nsc, wg, bg, xn, topk_idx, topk_gate,
                                        counts);
  k_scan<<<1, 64, 0, stream>>>(counts, offsets, cursor);
  k_fill<<<16, 256, 0, stream>>>(topk_idx, topk_gate, cursor, rows_tok, rows_gate);
  k_gather<<<dim3(128, NE), 256, 0, stream>>>(xn, counts, offsets, rows_tok, xg);
  k_ffn1<<<dim3(NI2 / 32, NE), 256, 0, stream>>>(xg, w1, b1, counts, offsets,
                                                 s_tiled);
  k_ffn2<<<dim3(NH / 32, NE), 256, 0, stream>>>(s_tiled, w2, b2, counts, offsets,
                                                rows_tok, rows_gate, out);
}

// Round 5
// 429.966 us; speedup vs baseline: 1.0290x; 1.0290x over previous
//
#include <hip/hip_runtime.h>

#define NH 1024   // hidden
#define NI2 2048  // 2*intermediate
#define NI 1024   // intermediate
#define NE 16     // experts
#define NT 1024   // tokens (2*512)

static constexpr float LIMITF = 7.0f;
static constexpr float ALPHAF = 1.702f;
static constexpr float EPSF = 1e-5f;

typedef short bf16x8 __attribute__((ext_vector_type(8)));
typedef float f32x16 __attribute__((ext_vector_type(16)));

__device__ __forceinline__ unsigned short f2bf(float f) {
  unsigned int u = __builtin_bit_cast(unsigned int, f);
  u = (u + 0x7FFFu + ((u >> 16) & 1u)) >> 16;
  return (unsigned short)u;
}

// async 16B global -> LDS (DMA path, no VGPR round-trip).
typedef __attribute__((address_space(1))) const unsigned int as1_uint;
typedef __attribute__((address_space(3))) unsigned int as3_uint;
__device__ __forceinline__ void gload16(const void* g, void* l) {
  __builtin_amdgcn_global_load_lds((as1_uint*)g, (as3_uint*)l, 16, 0, 0);
}

// ---------------- out = x (residual base) ----------------
__global__ __launch_bounds__(256) void k_init(const float* __restrict__ x,
                                              float* __restrict__ out) {
  int i = blockIdx.x * 256 + threadIdx.x;
  reinterpret_cast<float4*>(out)[i] = reinterpret_cast<const float4*>(x)[i];
}

// ---------------- RMSNorm + router ----------------
__global__ __launch_bounds__(256) void k_norm_router(
    const float* __restrict__ x, const float* __restrict__ nsc,
    const float* __restrict__ wg, const float* __restrict__ bg,
    unsigned short* __restrict__ xn, int* __restrict__ topk_idx,
    float* __restrict__ topk_gate, int* __restrict__ counts) {
  int t = blockIdx.x;
  int tid = threadIdx.x;
  int wave = tid >> 6, lane = tid & 63;

  float4 v = reinterpret_cast<const float4*>(x + (size_t)t * NH)[tid];
  float ss = v.x * v.x + v.y * v.y + v.z * v.z + v.w * v.w;
  for (int off = 32; off; off >>= 1) ss += __shfl_xor(ss, off);

  __shared__ float red[4];
  __shared__ float redl[4][16];
  __shared__ float logits_s[16];
  if (lane == 0) red[wave] = ss;
  __syncthreads();
  float tot = red[0] + red[1] + red[2] + red[3];
  float r = rsqrtf(tot * (1.0f / NH) + EPSF);

  float4 sc = reinterpret_cast<const float4*>(nsc)[tid];
  float xv[4];
  xv[0] = v.x * r * sc.x;
  xv[1] = v.y * r * sc.y;
  xv[2] = v.z * r * sc.z;
  xv[3] = v.w * r * sc.w;

  ushort4 o;
  o.x = f2bf(xv[0]); o.y = f2bf(xv[1]); o.z = f2bf(xv[2]); o.w = f2bf(xv[3]);
  reinterpret_cast<ushort4*>(xn + (size_t)t * NH)[tid] = o;

  float acc[16];
#pragma unroll
  for (int e = 0; e < 16; e++) acc[e] = 0.f;
  int hbase = tid * 4;
#pragma unroll
  for (int i = 0; i < 4; i++) {
    const float4* wr = reinterpret_cast<const float4*>(wg + (size_t)(hbase + i) * NE);
#pragma unroll
    for (int j = 0; j < 4; j++) {
      float4 w = wr[j];
      acc[j * 4 + 0] += xv[i] * w.x;
      acc[j * 4 + 1] += xv[i] * w.y;
      acc[j * 4 + 2] += xv[i] * w.z;
      acc[j * 4 + 3] += xv[i] * w.w;
    }
  }
#pragma unroll
  for (int e = 0; e < 16; e++)
    for (int off = 32; off; off >>= 1) acc[e] += __shfl_xor(acc[e], off);
  if (lane == 0) {
#pragma unroll
    for (int e = 0; e < 16; e++) redl[wave][e] = acc[e];
  }
  __syncthreads();
  if (tid < 16)
    logits_s[tid] = redl[0][tid] + redl[1][tid] + redl[2][tid] + redl[3][tid] + bg[tid];
  __syncthreads();

  if (tid == 0) {
    float vals[16];
#pragma unroll
    for (int e = 0; e < 16; e++) vals[e] = logits_s[e];
    int sel[4]; float sv[4];
    unsigned used = 0;
    for (int k = 0; k < 4; k++) {
      float best = -1e30f; int bi = 0;
      for (int e = 0; e < 16; e++) {
        if (!((used >> e) & 1u) && vals[e] > best) { best = vals[e]; bi = e; }
      }
      used |= 1u << bi; sel[k] = bi; sv[k] = best;
    }
    float g[4], ssum = 0.f;
    for (int k = 0; k < 4; k++) { g[k] = __expf(sv[k] - sv[0]); ssum += g[k]; }
    for (int k = 0; k < 4; k++) {
      topk_idx[t * 4 + k] = sel[k];
      topk_gate[t * 4 + k] = g[k] / ssum;
      atomicAdd(&counts[sel[k]], 1);
    }
  }
}

// ---------------- prefix scan over 16 experts (32-aligned offsets) -------
__global__ void k_scan(const int* __restrict__ counts, int* __restrict__ offsets,
                       int* __restrict__ cursor) {
  if (blockIdx.x == 0 && threadIdx.x == 0) {
    int o = 0;
    for (int e = 0; e < NE; e++) {
      offsets[e] = o; cursor[e] = o;
      o += (counts[e] + 31) & ~31;   // pad each expert range to 32 slots
    }
  }
}

// ---------------- fill compact per-expert row lists ----------------
__global__ __launch_bounds__(256) void k_fill(const int* __restrict__ topk_idx,
                                              const float* __restrict__ topk_gate,
                                              int* __restrict__ cursor,
                                              int* __restrict__ rows_tok,
                                              float* __restrict__ rows_gate) {
  int idx = blockIdx.x * 256 + threadIdx.x;
  if (idx >= NT * 4) return;
  int e = topk_idx[idx];
  int slot = atomicAdd(&cursor[e], 1);
  rows_tok[slot] = idx >> 2;
  rows_gate[slot] = topk_gate[idx];
}

// ---------------- gather routed activations into MFMA-tiled layout ------
// xg layout: [group][k-octet 0..127][row-in-group 0..31][8 bf16]
__global__ __launch_bounds__(256) void k_gather(
    const unsigned short* __restrict__ xn, const int* __restrict__ counts,
    const int* __restrict__ offsets, const int* __restrict__ rows_tok,
    unsigned short* __restrict__ xg) {
  int e = blockIdx.y;
  int g = blockIdx.x;
  int cnt = counts[e];
  if (g * 32 >= cnt) return;
  int tid = threadIdx.x;
  int r = tid & 31, kq = tid >> 5;
  int rowbase = offsets[e];
  int tok = rows_tok[rowbase + min(g * 32 + r, cnt - 1)];
  const uint4* src = reinterpret_cast<const uint4*>(xn + (size_t)tok * NH);
  uint4* dst = reinterpret_cast<uint4*>(
      xg + ((size_t)(rowbase >> 5) + g) * (128 * 32 * 8));
#pragma unroll
  for (int i = 0; i < 16; i++) {
    int ko = i * 8 + kq;        // k-octet 0..127
    dst[ko * 32 + r] = src[ko]; // raw bf16x8 copy
  }
}

// Async-staged panel build (unchanged from R4).
template <int ROWSTRIDE>
__device__ __forceinline__ void stage_panel_async(
    const float* __restrict__ wsrc, unsigned short* __restrict__ panel,
    float* __restrict__ fbuf, int tid) {
  int colq = tid & 7;
  int rquot = tid >> 3;
  int col = tid & 31;
  int oct = tid >> 5;
  for (int r = 0; r < 8; r++) {
#pragma unroll
    for (int i = 0; i < 4; i++) {
      int row = r * 128 + i * 32 + rquot;
      gload16(wsrc + (size_t)row * ROWSTRIDE + colq * 4,
              (char*)fbuf + tid * 16 + i * 4096);
    }
    __syncthreads();
#pragma unroll
    for (int oo = 0; oo < 2; oo++) {
      int o = oct + oo * 8;
      float f[8];
#pragma unroll
      for (int j = 0; j < 8; j++) f[j] = fbuf[(o * 8 + j) * 32 + col];
      unsigned pk[4];
#pragma unroll
      for (int j = 0; j < 4; j++)
        pk[j] = (unsigned)f2bf(f[2 * j]) | ((unsigned)f2bf(f[2 * j + 1]) << 16);
      *reinterpret_cast<uint4*>(&panel[(size_t)((r * 16 + o) * 32 + col) * 8]) =
          *reinterpret_cast<const uint4*>(pk);
    }
    __syncthreads();
  }
}

// ---------------- FFN1: flat grid, expert pinned to XCD (b%8 == e%8) ----
// All 64 N-strips of expert e land on XCD e%8 -> its xg panel (~0.6 MB)
// stays L2-resident across the 64x reuse (was L3-thrash: ~10 MB/XCD mixed).
__global__ __launch_bounds__(256) void k_ffn1(
    const unsigned short* __restrict__ xg, const float* __restrict__ w1,
    const float* __restrict__ b1, const int* __restrict__ counts,
    const int* __restrict__ offsets, unsigned short* __restrict__ s_tiled) {
  int b = blockIdx.x;
  int j = b >> 3;                       // 0..127
  int e = (b & 7) + ((j >> 6) << 3);    // XCD pin: b%8 == e%8
  int n0 = (j & 63) * 32;
  int cnt = counts[e];
  if (cnt == 0) return;
  int rowbase = offsets[e];
  int tid = threadIdx.x;

  __shared__ __align__(16) unsigned short lds_b[128 * 32 * 8];
  __shared__ __align__(16) float lds_f[128 * 32];

  stage_panel_async<NI2>(w1 + (size_t)e * (NH * NI2) + n0, lds_b, lds_f, tid);

  int lane = tid & 63;
  int wave = tid >> 6;
  int lrow = lane & 31;
  int khalf = lane >> 5;

  float bias = b1[(size_t)e * NI2 + n0 + lrow];
  int parity = lrow & 1;

  for (int m0 = 0; m0 < cnt; m0 += 256) {
    int tb0 = m0 + wave * 32;
    int tb1 = m0 + 128 + wave * 32;
    const unsigned short* a0p =
        xg + ((size_t)((rowbase + tb0) >> 5) * 128 + khalf) * 256 + lrow * 8;

    f32x16 acc0 = {0.f,0.f,0.f,0.f,0.f,0.f,0.f,0.f,0.f,0.f,0.f,0.f,0.f,0.f,0.f,0.f};
    f32x16 acc1 = {0.f,0.f,0.f,0.f,0.f,0.f,0.f,0.f,0.f,0.f,0.f,0.f,0.f,0.f,0.f,0.f};
    bool dual = (m0 + 128) < cnt;

    if (dual) {
      const unsigned short* a1p =
          xg + ((size_t)((rowbase + tb1) >> 5) * 128 + khalf) * 256 + lrow * 8;
#pragma unroll 4
      for (int k2 = 0; k2 < 64; k2++) {
        bf16x8 av0 = *reinterpret_cast<const bf16x8*>(a0p + k2 * 512);
        bf16x8 av1 = *reinterpret_cast<const bf16x8*>(a1p + k2 * 512);
        bf16x8 bv = *reinterpret_cast<const bf16x8*>(
            &lds_b[(size_t)((k2 * 2 + khalf) * 32 + lrow) * 8]);
        acc0 = __builtin_amdgcn_mfma_f32_32x32x16_bf16(av0, bv, acc0, 0, 0, 0);
        acc1 = __builtin_amdgcn_mfma_f32_32x32x16_bf16(av1, bv, acc1, 0, 0, 0);
      }
    } else {
#pragma unroll 4
      for (int k2 = 0; k2 < 64; k2++) {
        bf16x8 av0 = *reinterpret_cast<const bf16x8*>(a0p + k2 * 512);
        bf16x8 bv = *reinterpret_cast<const bf16x8*>(
            &lds_b[(size_t)((k2 * 2 + khalf) * 32 + lrow) * 8]);
        acc0 = __builtin_amdgcn_mfma_f32_32x32x16_bf16(av0, bv, acc0, 0, 0, 0);
      }
    }

#pragma unroll
    for (int t2 = 0; t2 < 2; t2++) {
      if (t2 == 1 && !dual) break;
      f32x16 acc = t2 ? acc1 : acc0;
      int tb = t2 ? tb1 : tb0;
#pragma unroll
      for (int reg = 0; reg < 16; reg++) {
        float v = acc[reg] + bias;
        float p = __shfl_xor(v, 1);
        int row = (reg & 3) + 8 * (reg >> 2) + 4 * khalf;
        int m = tb + row;
        if (!parity && m < cnt) {
          float aa = fminf(v, LIMITF);
          float bb = fminf(fmaxf(p, -LIMITF), LIMITF);
          float sig = 1.0f / (1.0f + __expf(-ALPHAF * aa));
          float sval = aa * sig * (bb + 1.0f);
          int c = (n0 + lrow) >> 1;  // intermediate column
          size_t grp = (size_t)(rowbase + tb) >> 5;
          s_tiled[(grp * 128 + (c >> 3)) * 256 + row * 8 + (c & 7)] = f2bf(sval);
        }
      }
    }
  }
}

// ---------------- FFN2: flat grid, same expert->XCD pinning -------------
__global__ __launch_bounds__(256) void k_ffn2(
    const unsigned short* __restrict__ s_tiled, const float* __restrict__ w2,
    const float* __restrict__ b2, const int* __restrict__ counts,
    const int* __restrict__ offsets, const int* __restrict__ rows_tok,
    const float* __restrict__ rows_gate, float* __restrict__ out) {
  int b = blockIdx.x;
  int j = b >> 3;                       // 0..63
  int e = (b & 7) + ((j >> 5) << 3);    // XCD pin: b%8 == e%8
  int n0 = (j & 31) * 32;
  int cnt = counts[e];
  if (cnt == 0) return;
  int rowbase = offsets[e];
  int tid = threadIdx.x;

  __shared__ __align__(16) unsigned short lds_b[128 * 32 * 8];
  __shared__ __align__(16) float lds_f[128 * 32];

  stage_panel_async<NH>(w2 + (size_t)e * (NI * NH) + n0, lds_b, lds_f, tid);

  int lane = tid & 63;
  int wave = tid >> 6;
  int lrow = lane & 31;
  int khalf = lane >> 5;

  float b2v = b2[(size_t)e * NH + n0 + lrow];

  for (int m0 = 0; m0 < cnt; m0 += 256) {
    int tb0 = m0 + wave * 32;
    int tb1 = m0 + 128 + wave * 32;
    const unsigned short* a0p =
        s_tiled + ((size_t)((rowbase + tb0) >> 5) * 128 + khalf) * 256 + lrow * 8;

    f32x16 acc0 = {0.f,0.f,0.f,0.f,0.f,0.f,0.f,0.f,0.f,0.f,0.f,0.f,0.f,0.f,0.f,0.f};
    f32x16 acc1 = {0.f,0.f,0.f,0.f,0.f,0.f,0.f,0.f,0.f,0.f,0.f,0.f,0.f,0.f,0.f,0.f};
    bool dual = (m0 + 128) < cnt;

    if (dual) {
      const unsigned short* a1p =
          s_tiled + ((size_t)((rowbase + tb1) >> 5) * 128 + khalf) * 256 + lrow * 8;
#pragma unroll 4
      for (int k2 = 0; k2 < 64; k2++) {
        bf16x8 av0 = *reinterpret_cast<const bf16x8*>(a0p + k2 * 512);
        bf16x8 av1 = *reinterpret_cast<const bf16x8*>(a1p + k2 * 512);
        bf16x8 bv = *reinterpret_cast<const bf16x8*>(
            &lds_b[(size_t)((k2 * 2 + khalf) * 32 + lrow) * 8]);
        acc0 = __builtin_amdgcn_mfma_f32_32x32x16_bf16(av0, bv, acc0, 0, 0, 0);
        acc1 = __builtin_amdgcn_mfma_f32_32x32x16_bf16(av1, bv, acc1, 0, 0, 0);
      }
    } else {
#pragma unroll 4
      for (int k2 = 0; k2 < 64; k2++) {
        bf16x8 av0 = *reinterpret_cast<const bf16x8*>(a0p + k2 * 512);
        bf16x8 bv = *reinterpret_cast<const bf16x8*>(
            &lds_b[(size_t)((k2 * 2 + khalf) * 32 + lrow) * 8]);
        acc0 = __builtin_amdgcn_mfma_f32_32x32x16_bf16(av0, bv, acc0, 0, 0, 0);
      }
    }

#pragma unroll
    for (int t2 = 0; t2 < 2; t2++) {
      if (t2 == 1 && !dual) break;
      f32x16 acc = t2 ? acc1 : acc0;
      int tb = t2 ? tb1 : tb0;
#pragma unroll
      for (int reg = 0; reg < 16; reg++) {
        int row = (reg & 3) + 8 * (reg >> 2) + 4 * khalf;
        int m = tb + row;
        if (m < cnt) {
          int rr = rowbase + m;           // wave-uniform per (reg,khalf)
          int tok = rows_tok[rr];
          float g = rows_gate[rr];
          atomicAdd(&out[(size_t)tok * NH + n0 + lrow], g * (acc[reg] + b2v));
        }
      }
    }
  }
}

extern "C" void kernel_launch(void* const* d_in, const int* in_sizes, int n_in,
                              void* d_out, int out_size, void* d_ws, size_t ws_size,
                              hipStream_t stream) {
  const float* x   = (const float*)d_in[0];
  const float* nsc = (const float*)d_in[1];
  const float* wg  = (const float*)d_in[2];
  const float* bg  = (const float*)d_in[3];
  const float* w1  = (const float*)d_in[4];
  const float* b1  = (const float*)d_in[5];
  const float* w2  = (const float*)d_in[6];
  const float* b2  = (const float*)d_in[7];
  float* out = (float*)d_out;
  char* ws = (char*)d_ws;

  // Workspace map (worst case 4576 padded slots = 143 groups):
  //   0       counts/offsets/cursor (zeroed)
  //   1024    topk_idx   16 KB
  //   17408   topk_gate  16 KB
  //   33792   rows_tok   20 KB (5120 slots >= 4576)
  //   54272   rows_gate  20 KB (5120 slots)
  //   131072  xn         2 MB
  //   2228224 xg         143*64KB = 9.15 MB
  //   12 MB   s_tiled    9.15 MB
  int*   counts    = (int*)(ws + 0);
  int*   offsets   = (int*)(ws + 64);
  int*   cursor    = (int*)(ws + 128);
  int*   topk_idx  = (int*)(ws + 1024);
  float* topk_gate = (float*)(ws + 17408);
  int*   rows_tok  = (int*)(ws + 33792);
  float* rows_gate = (float*)(ws + 54272);
  unsigned short* xn      = (unsigned short*)(ws + 131072);
  unsigned short* xg      = (unsigned short*)(ws + 2228224);
  unsigned short* s_tiled = (unsigned short*)(ws + 12 * 1024 * 1024);

  hipMemsetAsync(ws, 0, 256, stream);
  k_init<<<NT * NH / 1024, 256, 0, stream>>>(x, out);
  k_norm_router<<<NT, 256, 0, stream>>>(x, nsc, wg, bg, xn, topk_idx, topk_gate,
                                        counts);
  k_scan<<<1, 64, 0, stream>>>(counts, offsets, cursor);
  k_fill<<<16, 256, 0, stream>>>(topk_idx, topk_gate, cursor, rows_tok, rows_gate);
  k_gather<<<dim3(128, NE), 256, 0, stream>>>(xn, counts, offsets, rows_tok, xg);
  k_ffn1<<<1024, 256, 0, stream>>>(xg, w1, b1, counts, offsets, s_tiled);
  k_ffn2<<<512, 256, 0, stream>>>(s_tiled, w2, b2, counts, offsets,
                                  rows_tok, rows_gate, out);
}